// Round 1
// baseline (315.518 us; speedup 1.0000x reference)
//
#include <hip/hip_runtime.h>
#include <stdint.h>

using bf16x8 = __attribute__((ext_vector_type(8))) short;
using f32x4  = __attribute__((ext_vector_type(4))) float;

__device__ __forceinline__ unsigned short f2bf(float f) {
  union { float f; uint32_t u; } v; v.f = f;
  uint32_t r = v.u + 0x7FFFu + ((v.u >> 16) & 1u);
  return (unsigned short)(r >> 16);
}
__device__ __forceinline__ uint32_t pk2(float a, float b) {
  return (uint32_t)f2bf(a) | ((uint32_t)f2bf(b) << 16);
}
__device__ __forceinline__ f32x4 mfma16(bf16x8 a, bf16x8 b, f32x4 c) {
  return __builtin_amdgcn_mfma_f32_16x16x32_bf16(a, b, c, 0, 0, 0);
}

// ---------------- Kernel 1: per-pixel LayerNorm stats (mu, rstd) ----------------
__global__ __launch_bounds__(256) void k_lnstats(
    const float* __restrict__ xl, const float* __restrict__ xr,
    float* __restrict__ muW, float* __restrict__ rsW)
{
  const int blk  = blockIdx.x;        // 0..127 : side*64 + b
  const int side = blk >> 6, b = blk & 63;
  const float* x = (side ? xr : xl) + (size_t)b * 131072;
  const int t = threadIdx.x;
  const int p0 = t * 4;
  float s0=0,s1=0,s2=0,s3=0,q0=0,q1=0,q2=0,q3=0;
  for (int c = 0; c < 128; ++c) {
    const float4 v = *(const float4*)(x + c*1024 + p0);
    s0+=v.x; q0+=v.x*v.x; s1+=v.y; q1+=v.y*v.y;
    s2+=v.z; q2+=v.z*v.z; s3+=v.w; q3+=v.w*v.w;
  }
  const int o = (side*64 + b)*1024 + p0;
  float4 mu, rs;
  mu.x = s0*(1.0f/128.0f); mu.y = s1*(1.0f/128.0f);
  mu.z = s2*(1.0f/128.0f); mu.w = s3*(1.0f/128.0f);
  rs.x = rsqrtf(fmaxf(q0*(1.0f/128.0f) - mu.x*mu.x, 0.0f) + 1e-6f);
  rs.y = rsqrtf(fmaxf(q1*(1.0f/128.0f) - mu.y*mu.y, 0.0f) + 1e-6f);
  rs.z = rsqrtf(fmaxf(q2*(1.0f/128.0f) - mu.z*mu.z, 0.0f) + 1e-6f);
  rs.w = rsqrtf(fmaxf(q3*(1.0f/128.0f) - mu.w*mu.w, 0.0f) + 1e-6f);
  *(float4*)(muW + o) = mu;
  *(float4*)(rsW + o) = rs;
}

// ---------------- Kernel 2: conv4x4/s4 as GEMM (fused LN for Q path) ----------------
// grid 64: blockIdx.x = ctype*16 + mblk ; ctype: 0 Ql, 1 Qr, 2 Vl, 3 Vr
// block handles M=256 positions (4 images), N=128, K=2048 in 32-chunks.
__global__ __launch_bounds__(256) void k_conv(
    const float* __restrict__ xl, const float* __restrict__ xr,
    const float* __restrict__ lnwl, const float* __restrict__ lnbl,
    const float* __restrict__ lnwr, const float* __restrict__ lnbr,
    const float* __restrict__ Wl1, const float* __restrict__ bl1,
    const float* __restrict__ Wr1, const float* __restrict__ br1,
    const float* __restrict__ Wl2, const float* __restrict__ bl2,
    const float* __restrict__ Wr2, const float* __restrict__ br2,
    const float* __restrict__ pos,
    const float* __restrict__ muA, const float* __restrict__ rsA,
    unsigned short* __restrict__ Qbf, unsigned short* __restrict__ Vtbf)
{
  const int bx = blockIdx.x;
  const int ctype = bx >> 4;
  const int mblk  = bx & 15;
  const int side  = ctype & 1;
  const bool isQ  = ctype < 2;
  const float* x    = side ? xr : xl;
  const float* W    = (ctype==0)?Wl1:(ctype==1)?Wr1:(ctype==2)?Wl2:Wr2;
  const float* bias = (ctype==0)?bl1:(ctype==1)?br1:(ctype==2)?bl2:br2;
  const float* lnw  = side ? lnwr : lnwl;
  const float* lnb  = side ? lnbr : lnbl;
  const float* mu   = muA + side*65536;
  const float* rs   = rsA + side*65536;

  const int t = threadIdx.x;
  const int w = t >> 6, l = t & 63, lo = l & 15, g = l >> 4;
  const int b0 = mblk*4, p0 = mblk*256;
  const int img = w, lt = l;

  __shared__ __align__(16) unsigned char At[256*80];  // [pos][32 bf16 + pad]
  __shared__ __align__(16) unsigned char Bt[128*80];  // [c_out][32 bf16 + pad]

  f32x4 acc[4][8];
#pragma unroll
  for (int a=0;a<4;a++)
#pragma unroll
    for (int b=0;b<8;b++) acc[a][b] = (f32x4)0.0f;

  for (int kb = 0; kb < 64; ++kb) {
    // ---- stage A: 2 channels x 4 images, LN applied for Q path ----
#pragma unroll
    for (int cp = 0; cp < 2; ++cp) {
      const int c = 2*kb + cp;
      const float lw = lnw[c], lb = lnb[c];
#pragma unroll
      for (int j = 0; j < 4; ++j) {
        const int f4  = lt + 64*j;          // 0..255 float4 idx within (img,c)
        const int y   = f4 >> 3, xs4 = f4 & 7;
        const int h   = y >> 2, r = y & 3;
        const int row = img*64 + h*8 + xs4;
        const int pix = y*32 + xs4*4;
        const float4 v = *(const float4*)(x + (size_t)((b0+img)*128 + c)*1024 + pix);
        float a0=v.x, a1=v.y, a2=v.z, a3=v.w;
        if (isQ) {
          const float4 m  = *(const float4*)(mu + (b0+img)*1024 + pix);
          const float4 rv = *(const float4*)(rs + (b0+img)*1024 + pix);
          a0 = (a0-m.x)*rv.x*lw + lb; a1 = (a1-m.y)*rv.y*lw + lb;
          a2 = (a2-m.z)*rv.z*lw + lb; a3 = (a3-m.w)*rv.w*lw + lb;
        }
        *(uint2*)(At + row*80 + cp*32 + r*8) = make_uint2(pk2(a0,a1), pk2(a2,a3));
      }
    }
    // ---- stage B: W[c_out][kb*32..+31] -> Bt[c_out][k] bf16 ----
    {
      const int cw = t >> 1, half = t & 1;
      const float* wsrc = W + (size_t)cw*2048 + kb*32 + half*16;
      const float4 w0 = *(const float4*)(wsrc+0),  w1 = *(const float4*)(wsrc+4);
      const float4 w2 = *(const float4*)(wsrc+8),  w3 = *(const float4*)(wsrc+12);
      uint4 pa, pb;
      pa.x = pk2(w0.x,w0.y); pa.y = pk2(w0.z,w0.w); pa.z = pk2(w1.x,w1.y); pa.w = pk2(w1.z,w1.w);
      pb.x = pk2(w2.x,w2.y); pb.y = pk2(w2.z,w2.w); pb.z = pk2(w3.x,w3.y); pb.w = pk2(w3.z,w3.w);
      *(uint4*)(Bt + cw*80 + half*32)      = pa;
      *(uint4*)(Bt + cw*80 + half*32 + 16) = pb;
    }
    __syncthreads();
    // ---- MFMA ----
    bf16x8 af[4];
#pragma unroll
    for (int mf = 0; mf < 4; ++mf)
      af[mf] = *(const bf16x8*)(At + (w*64 + mf*16 + lo)*80 + g*16);
#pragma unroll
    for (int nf = 0; nf < 8; ++nf) {
      const bf16x8 bb = *(const bf16x8*)(Bt + (nf*16 + lo)*80 + g*16);
#pragma unroll
      for (int mf = 0; mf < 4; ++mf)
        acc[mf][nf] = mfma16(af[mf], bb, acc[mf][nf]);
    }
    __syncthreads();
  }
  // ---- epilogue: +bias +pos (Q: *sqrt(scale), row-major ; V: transposed) ----
  if (isQ) {
    unsigned short* Qo = Qbf + (size_t)side*524288;
#pragma unroll
    for (int mf = 0; mf < 4; ++mf)
#pragma unroll
      for (int nf = 0; nf < 8; ++nf) {
        const int co = nf*16 + lo;
#pragma unroll
        for (int rr = 0; rr < 4; ++rr) {
          const int pi = mf*16 + g*4 + rr;
          const int p  = p0 + w*64 + pi;
          float val = acc[mf][nf][rr] + bias[co] + pos[co*64 + pi];
          val *= 0.105112052f;  // sqrt(1/(8*sqrt(128))) baked into both Qs
          Qo[(size_t)p*128 + co] = f2bf(val);
        }
      }
  } else {
    unsigned short* Vo = Vtbf + (size_t)side*524288;
#pragma unroll
    for (int mf = 0; mf < 4; ++mf)
#pragma unroll
      for (int nf = 0; nf < 8; ++nf) {
        const int co = nf*16 + lo;
        float v0,v1,v2,v3;
        {
          const int pi0 = mf*16 + g*4;
          v0 = acc[mf][nf][0] + bias[co] + pos[co*64 + pi0];
          v1 = acc[mf][nf][1] + bias[co] + pos[co*64 + pi0 + 1];
          v2 = acc[mf][nf][2] + bias[co] + pos[co*64 + pi0 + 2];
          v3 = acc[mf][nf][3] + bias[co] + pos[co*64 + pi0 + 3];
        }
        *(uint2*)(Vo + (size_t)co*4096 + p0 + w*64 + mf*16 + g*4) =
            make_uint2(pk2(v0,v1), pk2(v2,v3));
      }
  }
}

// ---------------- Kernel 3: global cross-attention, flash-style, no-max softmax ----------------
// grid (128, 2): qb, dir. 32 query rows per block, 64-key tiles.
__global__ __launch_bounds__(256) void k_attn(
    const unsigned short* __restrict__ Qbf,
    const unsigned short* __restrict__ Vtbf,
    unsigned short* __restrict__ Fbf)
{
  const int qb = blockIdx.x, dir = blockIdx.y;
  const unsigned short* Qp = Qbf  + (size_t)dir*524288;
  const unsigned short* Kp = Qbf  + (size_t)(1-dir)*524288;
  const unsigned short* Vp = Vtbf + (size_t)(1-dir)*524288;
  unsigned short*       Fo = Fbf  + (size_t)dir*524288;

  const int t = threadIdx.x;
  const int w = t >> 6, l = t & 63, lo = l & 15, g = l >> 4;

  __shared__ __align__(16) unsigned char ldsK[16384]; // [64 k][128 c] bf16, swz
  __shared__ __align__(16) unsigned char ldsV[16384]; // [128 c][64 k] bf16, swz
  __shared__ __align__(16) unsigned char ldsP[4096];  // [32 q][64 k] bf16, swz
  __shared__ float lred[4][32];

  bf16x8 aq[2][4];
#pragma unroll
  for (int mf = 0; mf < 2; ++mf)
#pragma unroll
    for (int kc = 0; kc < 4; ++kc)
      aq[mf][kc] = *(const bf16x8*)(Qp + (size_t)(qb*32 + mf*16 + lo)*128 + kc*32 + g*8);

  f32x4 o[2][2];
  o[0][0]=(f32x4)0.0f; o[0][1]=(f32x4)0.0f; o[1][0]=(f32x4)0.0f; o[1][1]=(f32x4)0.0f;
  float ls[2][4] = {{0,0,0,0},{0,0,0,0}};

  for (int kt = 0; kt < 64; ++kt) {
    __syncthreads();  // protect K/V/P from previous iteration's readers
    // stage K tile (contiguous 16 KB), swizzled
    {
      const uint4* src = (const uint4*)(Kp + (size_t)kt*8192);
#pragma unroll
      for (int j = 0; j < 4; ++j) {
        const int idx = t + 256*j;
        const int dst = idx*16;
        const int row = dst >> 8;
        *(uint4*)(ldsK + dst) = src[(dst ^ ((row & 7) << 4)) >> 4];
      }
      // stage V^T tile: rows c, 64 keys each, swizzled
#pragma unroll
      for (int j = 0; j < 4; ++j) {
        const int idx = t + 256*j;
        const int c = idx >> 3, i = idx & 7;
        const int inrow = (i*16) ^ ((c & 7) << 4);  // logical byte for slot i*16
        const uint4 v = *(const uint4*)(Vp + (size_t)c*4096 + kt*64 + (inrow >> 1));
        *(uint4*)(ldsV + c*128 + i*16) = v;
      }
    }
    __syncthreads();
    // QK^T : S[q][k]  (q rows via A=Q regs, k cols via B from ldsK)
    f32x4 s[2]; s[0] = (f32x4)0.0f; s[1] = (f32x4)0.0f;
    const int krow = w*16 + lo;
#pragma unroll
    for (int kc = 0; kc < 4; ++kc) {
      const bf16x8 bk = *(const bf16x8*)(ldsK + krow*256 + ((kc*64 + g*16) ^ ((krow & 7) << 4)));
      s[0] = mfma16(aq[0][kc], bk, s[0]);
      s[1] = mfma16(aq[1][kc], bk, s[1]);
    }
    // exp (no max needed: logits are small), write P, accumulate denom
#pragma unroll
    for (int mf = 0; mf < 2; ++mf)
#pragma unroll
      for (int rr = 0; rr < 4; ++rr) {
        const float e = __expf(s[mf][rr]);
        ls[mf][rr] += e;
        const int q = mf*16 + g*4 + rr;
        const int inrow = (w*32 + lo*2) ^ ((q & 7) << 4);
        *(unsigned short*)(ldsP + q*128 + inrow) = f2bf(e);
      }
    __syncthreads();
    // PV : O[q][c] += P[q][k] * V[k][c]
#pragma unroll
    for (int kd = 0; kd < 2; ++kd) {
      bf16x8 pa[2];
#pragma unroll
      for (int mf = 0; mf < 2; ++mf) {
        const int q = mf*16 + lo;
        pa[mf] = *(const bf16x8*)(ldsP + q*128 + ((kd*64 + g*16) ^ ((q & 7) << 4)));
      }
#pragma unroll
      for (int nf = 0; nf < 2; ++nf) {
        const int c = w*32 + nf*16 + lo;
        const bf16x8 bv = *(const bf16x8*)(ldsV + c*128 + ((kd*64 + g*16) ^ ((c & 7) << 4)));
        o[0][nf] = mfma16(pa[0], bv, o[0][nf]);
        o[1][nf] = mfma16(pa[1], bv, o[1][nf]);
      }
    }
  }
  // reduce denominators across the 16 key-lanes, then across waves
#pragma unroll
  for (int mf = 0; mf < 2; ++mf)
#pragma unroll
    for (int rr = 0; rr < 4; ++rr) {
      float v = ls[mf][rr];
      v += __shfl_xor(v, 1, 64);
      v += __shfl_xor(v, 2, 64);
      v += __shfl_xor(v, 4, 64);
      v += __shfl_xor(v, 8, 64);
      ls[mf][rr] = v;
    }
  if (lo == 0) {
#pragma unroll
    for (int mf = 0; mf < 2; ++mf)
#pragma unroll
      for (int rr = 0; rr < 4; ++rr)
        lred[w][mf*16 + g*4 + rr] = ls[mf][rr];
  }
  __syncthreads();
#pragma unroll
  for (int mf = 0; mf < 2; ++mf)
#pragma unroll
    for (int rr = 0; rr < 4; ++rr) {
      const int q = mf*16 + g*4 + rr;
      const float inv = 1.0f / (lred[0][q] + lred[1][q] + lred[2][q] + lred[3][q]);
#pragma unroll
      for (int nf = 0; nf < 2; ++nf) {
        const int c = w*32 + nf*16 + lo;
        Fo[(size_t)(qb*32 + q)*128 + c] = f2bf(o[mf][nf][rr] * inv);
      }
    }
}

// ---------------- Kernel 4: projection + pixel-shuffle + residual ----------------
// grid (16, 64, 2): nb (128 of 2048 outs), mb (image), side
__global__ __launch_bounds__(256) void k_proj(
    const unsigned short* __restrict__ Fbf,
    const float* __restrict__ Wl3, const float* __restrict__ bl3,
    const float* __restrict__ Wr3, const float* __restrict__ br3,
    const float* __restrict__ beta, const float* __restrict__ gamma,
    const float* __restrict__ xl, const float* __restrict__ xr,
    float* __restrict__ out)
{
  const int nb = blockIdx.x, mb = blockIdx.y, side = blockIdx.z;
  const unsigned short* F = Fbf + (size_t)side*524288;
  const float* W3  = side ? Wr3 : Wl3;
  const float* b3  = side ? br3 : bl3;
  const float* scl = side ? gamma : beta;
  const float* xin = side ? xr : xl;
  float* op = out + (size_t)side*8388608;

  const int t = threadIdx.x;
  const int w = t >> 6, l = t & 63, lo = l & 15, g = l >> 4;

  __shared__ __align__(16) unsigned char Ft[16384];  // [64 pos][128 c] bf16, swz
  __shared__ __align__(16) unsigned char B3[32768];  // [128 n][128 c] bf16, swz

  {
    const uint4* src = (const uint4*)(F + (size_t)mb*8192);
#pragma unroll
    for (int j = 0; j < 4; ++j) {
      const int idx = t + 256*j;
      const int dst = idx*16;
      const int row = dst >> 8;
      *(uint4*)(Ft + dst) = src[(dst ^ ((row & 7) << 4)) >> 4];
    }
  }
  {
    const int nl = t >> 1, half = t & 1;
    const float* wsrc = W3 + (size_t)(nb*128 + nl)*128 + half*64;
#pragma unroll
    for (int ch = 0; ch < 8; ++ch) {
      const float4 v0 = *(const float4*)(wsrc + ch*8);
      const float4 v1 = *(const float4*)(wsrc + ch*8 + 4);
      uint4 pk;
      pk.x = pk2(v0.x,v0.y); pk.y = pk2(v0.z,v0.w);
      pk.z = pk2(v1.x,v1.y); pk.w = pk2(v1.z,v1.w);
      const int inrow = (half*128 + ch*16) ^ ((nl & 7) << 4);
      *(uint4*)(B3 + nl*256 + inrow) = pk;
    }
  }
  __syncthreads();

  f32x4 acc[4][2];
#pragma unroll
  for (int a=0;a<4;a++) { acc[a][0] = (f32x4)0.0f; acc[a][1] = (f32x4)0.0f; }

  bf16x8 af[4][4];
#pragma unroll
  for (int mf = 0; mf < 4; ++mf) {
    const int row = mf*16 + lo;
#pragma unroll
    for (int kc = 0; kc < 4; ++kc)
      af[mf][kc] = *(const bf16x8*)(Ft + row*256 + ((kc*64 + g*16) ^ ((row & 7) << 4)));
  }
#pragma unroll
  for (int kc = 0; kc < 4; ++kc)
#pragma unroll
    for (int nf = 0; nf < 2; ++nf) {
      const int n = w*32 + nf*16 + lo;
      const bf16x8 bb = *(const bf16x8*)(B3 + n*256 + ((kc*64 + g*16) ^ ((n & 7) << 4)));
#pragma unroll
      for (int mf = 0; mf < 4; ++mf)
        acc[mf][nf] = mfma16(af[mf][kc], bb, acc[mf][nf]);
    }

#pragma unroll
  for (int mf = 0; mf < 4; ++mf)
#pragma unroll
    for (int nf = 0; nf < 2; ++nf) {
      const int n16 = nb*128 + w*32 + nf*16 + lo;
      const int c = n16 >> 4, r4 = (n16 >> 2) & 3, sc = n16 & 3;
      const float scc = scl[c];
      const float bb3 = b3[n16];
#pragma unroll
      for (int rr = 0; rr < 4; ++rr) {
        const int pi = mf*16 + g*4 + rr;     // position within image: h*8+w
        const int h = pi >> 3, wc = pi & 7;
        const size_t oidx = ((size_t)(mb*128 + c))*1024 + (size_t)(h*4 + r4)*32 + wc*4 + sc;
        op[oidx] = xin[oidx] + scc*(acc[mf][nf][rr] + bb3);
      }
    }
}

extern "C" void kernel_launch(void* const* d_in, const int* in_sizes, int n_in,
                              void* d_out, int out_size, void* d_ws, size_t ws_size,
                              hipStream_t stream) {
  (void)in_sizes; (void)n_in; (void)out_size; (void)ws_size;
  const float* xl   = (const float*)d_in[0];
  const float* xr   = (const float*)d_in[1];
  const float* lnwl = (const float*)d_in[2];
  const float* lnbl = (const float*)d_in[3];
  const float* lnwr = (const float*)d_in[4];
  const float* lnbr = (const float*)d_in[5];
  const float* Wl1  = (const float*)d_in[6];
  const float* bl1  = (const float*)d_in[7];
  const float* Wr1  = (const float*)d_in[8];
  const float* br1  = (const float*)d_in[9];
  const float* Wl2  = (const float*)d_in[10];
  const float* bl2  = (const float*)d_in[11];
  const float* Wr2  = (const float*)d_in[12];
  const float* br2  = (const float*)d_in[13];
  const float* pos  = (const float*)d_in[14];
  const float* beta = (const float*)d_in[15];
  const float* gamma= (const float*)d_in[16];
  const float* Wl3  = (const float*)d_in[17];
  const float* bl3  = (const float*)d_in[18];
  const float* Wr3  = (const float*)d_in[19];
  const float* br3  = (const float*)d_in[20];

  float* muW = (float*)d_ws;                        // [2][64][1024]
  float* rsW = muW + 131072;                        // [2][64][1024]
  unsigned short* Qbf  = (unsigned short*)(rsW + 131072); // [2][4096][128] bf16
  unsigned short* Vtbf = Qbf + 1048576;                   // [2][128][4096] bf16
  unsigned short* Fbf  = Vtbf + 1048576;                  // [2][4096][128] bf16

  k_lnstats<<<128, 256, 0, stream>>>(xl, xr, muW, rsW);
  k_conv<<<64, 256, 0, stream>>>(xl, xr, lnwl, lnbl, lnwr, lnbr,
      Wl1, bl1, Wr1, br1, Wl2, bl2, Wr2, br2, pos, muW, rsW, Qbf, Vtbf);
  k_attn<<<dim3(128, 2), 256, 0, stream>>>(Qbf, Vtbf, Fbf);
  k_proj<<<dim3(16, 64, 2), 256, 0, stream>>>(Fbf, Wl3, bl3, Wr3, br3,
      beta, gamma, xl, xr, (float*)d_out);
}

// Round 3
// 180.814 us; speedup vs baseline: 1.7450x; 1.7450x over previous
//
#include <hip/hip_runtime.h>
#include <stdint.h>

using bf16x8 = __attribute__((ext_vector_type(8))) short;
using f32x4  = __attribute__((ext_vector_type(4))) float;

__device__ __forceinline__ unsigned short f2bf(float f) {
  union { float f; uint32_t u; } v; v.f = f;
  uint32_t r = v.u + 0x7FFFu + ((v.u >> 16) & 1u);
  return (unsigned short)(r >> 16);
}
__device__ __forceinline__ uint32_t pk2(float a, float b) {
  return (uint32_t)f2bf(a) | ((uint32_t)f2bf(b) << 16);
}
__device__ __forceinline__ f32x4 mfma16(bf16x8 a, bf16x8 b, f32x4 c) {
  return __builtin_amdgcn_mfma_f32_16x16x32_bf16(a, b, c, 0, 0, 0);
}

// ---------------- Kernel 1: per-pixel LayerNorm stats (mu, rstd) ----------------
// grid 256: side(2) x img(64) x half(2); thread owns 2 pixels.
__global__ __launch_bounds__(256) void k_lnstats(
    const float* __restrict__ xl, const float* __restrict__ xr,
    float* __restrict__ muW, float* __restrict__ rsW)
{
  const int bx = blockIdx.x;
  const int side = bx >> 7, rem = bx & 127;
  const int b = rem >> 1, half = rem & 1;
  const float* x = (side ? xr : xl) + (size_t)b * 131072 + half * 512;
  const int t = threadIdx.x;
  const int px = t * 2;
  float s0=0, s1=0, q0=0, q1=0;
  for (int c = 0; c < 128; ++c) {
    const float2 v = *(const float2*)(x + c*1024 + px);
    s0 += v.x; q0 += v.x*v.x;
    s1 += v.y; q1 += v.y*v.y;
  }
  const int o = (side*64 + b)*1024 + half*512 + px;
  float2 mu, rs;
  mu.x = s0*(1.0f/128.0f); mu.y = s1*(1.0f/128.0f);
  rs.x = rsqrtf(fmaxf(q0*(1.0f/128.0f) - mu.x*mu.x, 0.0f) + 1e-6f);
  rs.y = rsqrtf(fmaxf(q1*(1.0f/128.0f) - mu.y*mu.y, 0.0f) + 1e-6f);
  *(float2*)(muW + o) = mu;
  *(float2*)(rsW + o) = rs;
}

// ---------------- Kernel 1b: weight prep ----------------
__global__ __launch_bounds__(256) void k_wprep(
    const float* __restrict__ lnwl, const float* __restrict__ lnbl,
    const float* __restrict__ lnwr, const float* __restrict__ lnbr,
    const float* __restrict__ Wl1, const float* __restrict__ bl1,
    const float* __restrict__ Wr1, const float* __restrict__ br1,
    const float* __restrict__ Wl2, const float* __restrict__ Wr2,
    unsigned short* __restrict__ Wq, unsigned short* __restrict__ Wv,
    float* __restrict__ bqW)
{
  const int bx = blockIdx.x;
  const int side = bx >> 7, co = bx & 127;
  const float* W1  = side ? Wr1 : Wl1;
  const float* W2  = side ? Wr2 : Wl2;
  const float* b1  = side ? br1 : bl1;
  const float* lnw = side ? lnwr : lnwl;
  const float* lnb = side ? lnbr : lnbl;
  const int t = threadIdx.x;
  const int ci = t >> 1;
  const float lw = lnw[ci], lb = lnb[ci];

  const float* src1 = W1 + (size_t)co*2048 + t*8;
  const float4 a0 = *(const float4*)(src1);
  const float4 a1 = *(const float4*)(src1 + 4);
  float part = (a0.x+a0.y+a0.z+a0.w + a1.x+a1.y+a1.z+a1.w) * lb;
  uint4 pkq;
  pkq.x = pk2(a0.x*lw, a0.y*lw); pkq.y = pk2(a0.z*lw, a0.w*lw);
  pkq.z = pk2(a1.x*lw, a1.y*lw); pkq.w = pk2(a1.z*lw, a1.w*lw);
  *(uint4*)(Wq + (size_t)side*262144 + co*2048 + t*8) = pkq;

  const float* src2 = W2 + (size_t)co*2048 + t*8;
  const float4 c0 = *(const float4*)(src2);
  const float4 c1 = *(const float4*)(src2 + 4);
  uint4 pkv;
  pkv.x = pk2(c0.x, c0.y); pkv.y = pk2(c0.z, c0.w);
  pkv.z = pk2(c1.x, c1.y); pkv.w = pk2(c1.z, c1.w);
  *(uint4*)(Wv + (size_t)side*262144 + co*2048 + t*8) = pkv;

  __shared__ float red[4];
  float v = part;
  v += __shfl_down(v, 32, 64); v += __shfl_down(v, 16, 64);
  v += __shfl_down(v, 8, 64);  v += __shfl_down(v, 4, 64);
  v += __shfl_down(v, 2, 64);  v += __shfl_down(v, 1, 64);
  if ((t & 63) == 0) red[t >> 6] = v;
  __syncthreads();
  if (t == 0) bqW[side*128 + co] = b1[co] + red[0] + red[1] + red[2] + red[3];
}

// ---------------- Kernel 2: conv4x4/s4 as per-image GEMM, double-buffered ----------------
// grid 256: ctype(4) x img(64). M=64 (patches), N=128 (couts), K=2048, BK=64.
__global__ __launch_bounds__(256) void k_conv(
    const float* __restrict__ xl, const float* __restrict__ xr,
    const unsigned short* __restrict__ Wq, const unsigned short* __restrict__ Wv,
    const float* __restrict__ bqW,
    const float* __restrict__ bl2, const float* __restrict__ br2,
    const float* __restrict__ pos,
    const float* __restrict__ muW, const float* __restrict__ rsW,
    unsigned short* __restrict__ Qbf, unsigned short* __restrict__ Vtbf)
{
  const int bx = blockIdx.x;
  const int ctype = bx >> 6, img = bx & 63;
  const int side = ctype & 1;
  const bool isQ = ctype < 2;
  const float* x = (side ? xr : xl) + (size_t)img * 131072;
  const unsigned short* Bsrc = (isQ ? Wq : Wv) + (size_t)side * 262144;

  const int t = threadIdx.x;
  const int w = t >> 6, l = t & 63, lo = l & 15, g = l >> 4;

  // LDS: [0,4K) mu, [4K,8K) rs, [8K,16K) A0, [16K,24K) A1, [24K,40K) B0, [40K,56K) B1
  __shared__ __align__(16) unsigned char lds[57344];
  float* muL = (float*)lds;
  float* rsL = (float*)(lds + 4096);

  if (isQ) {
    const int o = (side*64 + img)*1024 + t*4;
    *(float4*)(muL + t*4) = *(const float4*)(muW + o);
    *(float4*)(rsL + t*4) = *(const float4*)(rsW + o);
  }

  const int cl   = t >> 6;            // A: channel-local 0..3
  const int px0  = (t & 63) * 16;     // A: 16 consecutive pixels
  const int y    = px0 >> 5;
  const int wr   = y & 3;
  const int pbase = (y >> 2)*8 + ((px0 & 31) >> 2);
  const int cout = t >> 1, part = t & 1;   // B

  float4 av[4];
  bf16x8 bv[4];

  auto GLOAD = [&](int kb) {
    const float* xs = x + (size_t)(kb*4 + cl)*1024 + px0;
#pragma unroll
    for (int i = 0; i < 4; ++i) av[i] = *(const float4*)(xs + 4*i);
    const unsigned short* bs = Bsrc + (size_t)cout*2048 + kb*64 + part*32;
#pragma unroll
    for (int i = 0; i < 4; ++i) bv[i] = *(const bf16x8*)(bs + i*8);
  };
  auto SWRITE = [&](int buf) {
    unsigned char* A = lds + 8192  + (buf << 13);
    unsigned char* B = lds + 24576 + (buf << 14);
#pragma unroll
    for (int i = 0; i < 4; ++i) {
      const int p = pbase + i;
      float4 v = av[i];
      if (isQ) {
        const float4 m  = *(const float4*)(muL + px0 + 4*i);
        const float4 rv = *(const float4*)(rsL + px0 + 4*i);
        v.x = (v.x - m.x)*rv.x; v.y = (v.y - m.y)*rv.y;
        v.z = (v.z - m.z)*rv.z; v.w = (v.w - m.w)*rv.w;
      }
      int dst = p*128 + cl*32 + wr*8;
      dst ^= ((p ^ (p >> 3)) & 7) << 4;
      *(uint2*)(A + dst) = make_uint2(pk2(v.x, v.y), pk2(v.z, v.w));
    }
#pragma unroll
    for (int i = 0; i < 4; ++i) {
      const int dst = cout*128 + ((part*64 + i*16) ^ ((cout & 7) << 4));
      *(bf16x8*)(B + dst) = bv[i];
    }
  };

  f32x4 acc[4][2];
#pragma unroll
  for (int a = 0; a < 4; ++a) { acc[a][0] = (f32x4)0.0f; acc[a][1] = (f32x4)0.0f; }

  GLOAD(0);
  if (isQ) __syncthreads();   // mu/rs visible before SWRITE reads them
  SWRITE(0);

  int cur = 0;
  for (int kb = 0; kb < 32; ++kb) {
    __syncthreads();
    if (kb < 31) GLOAD(kb + 1);
    unsigned char* Ac = lds + 8192  + (cur << 13);
    unsigned char* Bc = lds + 24576 + (cur << 14);
    bf16x8 af[4][2], bfr[2][2];
#pragma unroll
    for (int mf = 0; mf < 4; ++mf) {
      const int row = mf*16 + lo;
      const int key = ((row ^ (row >> 3)) & 7) << 4;
#pragma unroll
      for (int kc = 0; kc < 2; ++kc)
        af[mf][kc] = *(const bf16x8*)(Ac + row*128 + ((kc*64 + g*16) ^ key));
    }
#pragma unroll
    for (int nf = 0; nf < 2; ++nf) {
      const int row = w*32 + nf*16 + lo;
      const int key = (row & 7) << 4;
#pragma unroll
      for (int kc = 0; kc < 2; ++kc)
        bfr[nf][kc] = *(const bf16x8*)(Bc + row*128 + ((kc*64 + g*16) ^ key));
    }
#pragma unroll
    for (int kc = 0; kc < 2; ++kc)
#pragma unroll
      for (int nf = 0; nf < 2; ++nf)
#pragma unroll
        for (int mf = 0; mf < 4; ++mf)
          acc[mf][nf] = mfma16(af[mf][kc], bfr[nf][kc], acc[mf][nf]);
    if (kb < 31) SWRITE(cur ^ 1);
    cur ^= 1;
  }

  // epilogue
  if (isQ) {
    unsigned short* Qo = Qbf + (size_t)side*524288;
    const float* bq = bqW + side*128;
#pragma unroll
    for (int mf = 0; mf < 4; ++mf)
#pragma unroll
      for (int nf = 0; nf < 2; ++nf) {
        const int co = w*32 + nf*16 + lo;
        const float bb = bq[co];
#pragma unroll
        for (int rr = 0; rr < 4; ++rr) {
          const int pi = mf*16 + g*4 + rr;
          const int p  = img*64 + pi;
          float val = (acc[mf][nf][rr] + bb + pos[co*64 + pi]) * 0.105112052f;
          Qo[(size_t)p*128 + co] = f2bf(val);
        }
      }
  } else {
    unsigned short* Vo = Vtbf + (size_t)side*524288;
    const float* b2 = side ? br2 : bl2;
#pragma unroll
    for (int mf = 0; mf < 4; ++mf)
#pragma unroll
      for (int nf = 0; nf < 2; ++nf) {
        const int co = w*32 + nf*16 + lo;
        const float bb = b2[co];
        const int pi0 = mf*16 + g*4;
        const float v0 = acc[mf][nf][0] + bb + pos[co*64 + pi0];
        const float v1 = acc[mf][nf][1] + bb + pos[co*64 + pi0 + 1];
        const float v2 = acc[mf][nf][2] + bb + pos[co*64 + pi0 + 2];
        const float v3 = acc[mf][nf][3] + bb + pos[co*64 + pi0 + 3];
        *(uint2*)(Vo + (size_t)co*4096 + img*64 + pi0) =
            make_uint2(pk2(v0, v1), pk2(v2, v3));
      }
  }
}

// ---------------- Kernel 3: global cross-attention, flash-style, no-max softmax ----------------
__global__ __launch_bounds__(256) void k_attn(
    const unsigned short* __restrict__ Qbf,
    const unsigned short* __restrict__ Vtbf,
    unsigned short* __restrict__ Fbf)
{
  const int qb = blockIdx.x, dir = blockIdx.y;
  const unsigned short* Qp = Qbf  + (size_t)dir*524288;
  const unsigned short* Kp = Qbf  + (size_t)(1-dir)*524288;
  const unsigned short* Vp = Vtbf + (size_t)(1-dir)*524288;
  unsigned short*       Fo = Fbf  + (size_t)dir*524288;

  const int t = threadIdx.x;
  const int w = t >> 6, l = t & 63, lo = l & 15, g = l >> 4;

  __shared__ __align__(16) unsigned char ldsK[16384];
  __shared__ __align__(16) unsigned char ldsV[16384];
  __shared__ __align__(16) unsigned char ldsP[4096];
  __shared__ float lred[4][32];

  bf16x8 aq[2][4];
#pragma unroll
  for (int mf = 0; mf < 2; ++mf)
#pragma unroll
    for (int kc = 0; kc < 4; ++kc)
      aq[mf][kc] = *(const bf16x8*)(Qp + (size_t)(qb*32 + mf*16 + lo)*128 + kc*32 + g*8);

  f32x4 o[2][2];
  o[0][0]=(f32x4)0.0f; o[0][1]=(f32x4)0.0f; o[1][0]=(f32x4)0.0f; o[1][1]=(f32x4)0.0f;
  float ls[2][4] = {{0,0,0,0},{0,0,0,0}};

  for (int kt = 0; kt < 64; ++kt) {
    __syncthreads();
    {
      const uint4* src = (const uint4*)(Kp + (size_t)kt*8192);
#pragma unroll
      for (int j = 0; j < 4; ++j) {
        const int idx = t + 256*j;
        const int dst = idx*16;
        const int row = dst >> 8;
        *(uint4*)(ldsK + dst) = src[(dst ^ ((row & 7) << 4)) >> 4];
      }
#pragma unroll
      for (int j = 0; j < 4; ++j) {
        const int idx = t + 256*j;
        const int c = idx >> 3, i = idx & 7;
        const int inrow = (i*16) ^ ((c & 7) << 4);
        const uint4 v = *(const uint4*)(Vp + (size_t)c*4096 + kt*64 + (inrow >> 1));
        *(uint4*)(ldsV + c*128 + i*16) = v;
      }
    }
    __syncthreads();
    f32x4 s[2]; s[0] = (f32x4)0.0f; s[1] = (f32x4)0.0f;
    const int krow = w*16 + lo;
#pragma unroll
    for (int kc = 0; kc < 4; ++kc) {
      const bf16x8 bk = *(const bf16x8*)(ldsK + krow*256 + ((kc*64 + g*16) ^ ((krow & 7) << 4)));
      s[0] = mfma16(aq[0][kc], bk, s[0]);
      s[1] = mfma16(aq[1][kc], bk, s[1]);
    }
#pragma unroll
    for (int mf = 0; mf < 2; ++mf)
#pragma unroll
      for (int rr = 0; rr < 4; ++rr) {
        const float e = __expf(s[mf][rr]);
        ls[mf][rr] += e;
        const int q = mf*16 + g*4 + rr;
        const int inrow = (w*32 + lo*2) ^ ((q & 7) << 4);
        *(unsigned short*)(ldsP + q*128 + inrow) = f2bf(e);
      }
    __syncthreads();
#pragma unroll
    for (int kd = 0; kd < 2; ++kd) {
      bf16x8 pa[2];
#pragma unroll
      for (int mf = 0; mf < 2; ++mf) {
        const int q = mf*16 + lo;
        pa[mf] = *(const bf16x8*)(ldsP + q*128 + ((kd*64 + g*16) ^ ((q & 7) << 4)));
      }
#pragma unroll
      for (int nf = 0; nf < 2; ++nf) {
        const int c = w*32 + nf*16 + lo;
        const bf16x8 bv = *(const bf16x8*)(ldsV + c*128 + ((kd*64 + g*16) ^ ((c & 7) << 4)));
        o[0][nf] = mfma16(pa[0], bv, o[0][nf]);
        o[1][nf] = mfma16(pa[1], bv, o[1][nf]);
      }
    }
  }
#pragma unroll
  for (int mf = 0; mf < 2; ++mf)
#pragma unroll
    for (int rr = 0; rr < 4; ++rr) {
      float v = ls[mf][rr];
      v += __shfl_xor(v, 1, 64);
      v += __shfl_xor(v, 2, 64);
      v += __shfl_xor(v, 4, 64);
      v += __shfl_xor(v, 8, 64);
      ls[mf][rr] = v;
    }
  if (lo == 0) {
#pragma unroll
    for (int mf = 0; mf < 2; ++mf)
#pragma unroll
      for (int rr = 0; rr < 4; ++rr)
        lred[w][mf*16 + g*4 + rr] = ls[mf][rr];
  }
  __syncthreads();
#pragma unroll
  for (int mf = 0; mf < 2; ++mf)
#pragma unroll
    for (int rr = 0; rr < 4; ++rr) {
      const int q = mf*16 + g*4 + rr;
      const float inv = 1.0f / (lred[0][q] + lred[1][q] + lred[2][q] + lred[3][q]);
#pragma unroll
      for (int nf = 0; nf < 2; ++nf) {
        const int c = w*32 + nf*16 + lo;
        Fo[(size_t)(qb*32 + q)*128 + c] = f2bf(o[mf][nf][rr] * inv);
      }
    }
}

// ---------------- Kernel 4: projection + pixel-shuffle + residual ----------------
__global__ __launch_bounds__(256) void k_proj(
    const unsigned short* __restrict__ Fbf,
    const float* __restrict__ Wl3, const float* __restrict__ bl3,
    const float* __restrict__ Wr3, const float* __restrict__ br3,
    const float* __restrict__ beta, const float* __restrict__ gamma,
    const float* __restrict__ xl, const float* __restrict__ xr,
    float* __restrict__ out)
{
  const int nb = blockIdx.x, mb = blockIdx.y, side = blockIdx.z;
  const unsigned short* F = Fbf + (size_t)side*524288;
  const float* W3  = side ? Wr3 : Wl3;
  const float* b3  = side ? br3 : bl3;
  const float* scl = side ? gamma : beta;
  const float* xin = side ? xr : xl;
  float* op = out + (size_t)side*8388608;

  const int t = threadIdx.x;
  const int w = t >> 6, l = t & 63, lo = l & 15, g = l >> 4;

  __shared__ __align__(16) unsigned char Ft[16384];
  __shared__ __align__(16) unsigned char B3[32768];

  {
    const uint4* src = (const uint4*)(F + (size_t)mb*8192);
#pragma unroll
    for (int j = 0; j < 4; ++j) {
      const int idx = t + 256*j;
      const int dst = idx*16;
      const int row = dst >> 8;
      *(uint4*)(Ft + dst) = src[(dst ^ ((row & 7) << 4)) >> 4];
    }
  }
  {
    const int nl = t >> 1, half = t & 1;
    const float* wsrc = W3 + (size_t)(nb*128 + nl)*128 + half*64;
#pragma unroll
    for (int ch = 0; ch < 8; ++ch) {
      const float4 v0 = *(const float4*)(wsrc + ch*8);
      const float4 v1 = *(const float4*)(wsrc + ch*8 + 4);
      uint4 pk;
      pk.x = pk2(v0.x,v0.y); pk.y = pk2(v0.z,v0.w);
      pk.z = pk2(v1.x,v1.y); pk.w = pk2(v1.z,v1.w);
      const int inrow = (half*128 + ch*16) ^ ((nl & 7) << 4);
      *(uint4*)(B3 + nl*256 + inrow) = pk;
    }
  }
  __syncthreads();

  f32x4 acc[4][2];
#pragma unroll
  for (int a=0;a<4;a++) { acc[a][0] = (f32x4)0.0f; acc[a][1] = (f32x4)0.0f; }

  bf16x8 af[4][4];
#pragma unroll
  for (int mf = 0; mf < 4; ++mf) {
    const int row = mf*16 + lo;
#pragma unroll
    for (int kc = 0; kc < 4; ++kc)
      af[mf][kc] = *(const bf16x8*)(Ft + row*256 + ((kc*64 + g*16) ^ ((row & 7) << 4)));
  }
#pragma unroll
  for (int kc = 0; kc < 4; ++kc)
#pragma unroll
    for (int nf = 0; nf < 2; ++nf) {
      const int n = w*32 + nf*16 + lo;
      const bf16x8 bb = *(const bf16x8*)(B3 + n*256 + ((kc*64 + g*16) ^ ((n & 7) << 4)));
#pragma unroll
      for (int mf = 0; mf < 4; ++mf)
        acc[mf][nf] = mfma16(af[mf][kc], bb, acc[mf][nf]);
    }

#pragma unroll
  for (int mf = 0; mf < 4; ++mf)
#pragma unroll
    for (int nf = 0; nf < 2; ++nf) {
      const int n16 = nb*128 + w*32 + nf*16 + lo;
      const int c = n16 >> 4, r4 = (n16 >> 2) & 3, sc = n16 & 3;
      const float scc = scl[c];
      const float bb3 = b3[n16];
#pragma unroll
      for (int rr = 0; rr < 4; ++rr) {
        const int pi = mf*16 + g*4 + rr;
        const int h = pi >> 3, wc = pi & 7;
        const size_t oidx = ((size_t)(mb*128 + c))*1024 + (size_t)(h*4 + r4)*32 + wc*4 + sc;
        op[oidx] = xin[oidx] + scc*(acc[mf][nf][rr] + bb3);
      }
    }
}

extern "C" void kernel_launch(void* const* d_in, const int* in_sizes, int n_in,
                              void* d_out, int out_size, void* d_ws, size_t ws_size,
                              hipStream_t stream) {
  (void)in_sizes; (void)n_in; (void)out_size; (void)ws_size;
  const float* xl   = (const float*)d_in[0];
  const float* xr   = (const float*)d_in[1];
  const float* lnwl = (const float*)d_in[2];
  const float* lnbl = (const float*)d_in[3];
  const float* lnwr = (const float*)d_in[4];
  const float* lnbr = (const float*)d_in[5];
  const float* Wl1  = (const float*)d_in[6];
  const float* bl1  = (const float*)d_in[7];
  const float* Wr1  = (const float*)d_in[8];
  const float* br1  = (const float*)d_in[9];
  const float* Wl2  = (const float*)d_in[10];
  const float* bl2  = (const float*)d_in[11];
  const float* Wr2  = (const float*)d_in[12];
  const float* br2  = (const float*)d_in[13];
  const float* pos  = (const float*)d_in[14];
  const float* beta = (const float*)d_in[15];
  const float* gamma= (const float*)d_in[16];
  const float* Wl3  = (const float*)d_in[17];
  const float* bl3  = (const float*)d_in[18];
  const float* Wr3  = (const float*)d_in[19];
  const float* br3  = (const float*)d_in[20];

  float* muW = (float*)d_ws;                         // [2][64][1024]
  float* rsW = muW + 131072;                         // [2][64][1024]
  float* bqW = rsW + 131072;                         // [2][128]
  unsigned short* Wq   = (unsigned short*)(bqW + 256);  // [2][128][2048]
  unsigned short* Wv   = Wq + 524288;                   // [2][128][2048]
  unsigned short* Qbf  = Wv + 524288;                   // [2][4096][128]
  unsigned short* Vtbf = Qbf + 1048576;                 // [2][128][4096]
  unsigned short* Fbf  = Vtbf + 1048576;                // [2][4096][128]

  k_lnstats<<<256, 256, 0, stream>>>(xl, xr, muW, rsW);
  k_wprep<<<256, 256, 0, stream>>>(lnwl, lnbl, lnwr, lnbr,
      Wl1, bl1, Wr1, br1, Wl2, Wr2, Wq, Wv, bqW);
  k_conv<<<256, 256, 0, stream>>>(xl, xr, Wq, Wv, bqW, bl2, br2, pos,
      muW, rsW, Qbf, Vtbf);
  k_attn<<<dim3(128, 2), 256, 0, stream>>>(Qbf, Vtbf, Fbf);
  k_proj<<<dim3(16, 64, 2), 256, 0, stream>>>(Fbf, Wl3, bl3, Wr3, br3,
      beta, gamma, xl, xr, (float*)d_out);
}